// Round 8
// baseline (832.922 us; speedup 1.0000x reference)
//
#include <hip/hip_runtime.h>

typedef __attribute__((ext_vector_type(8))) short short8;
typedef __attribute__((ext_vector_type(4))) float f32x4;
typedef unsigned short u16;

#define NTOK 49
#define NBLK 4096

// LDS pool (u16 units), 64 KB total -> 2 blocks/CU
#define XF 0        // x frags [rt4][ks8][64][8] = 16384 u16 (32 KB)
#define VY 16384    // 32 slots x 512 u16 (32 KB): v frag f of head h at slot f*8+h;
                    // y frag (rt, ks=h) at slot rt*8+h  (same 4 slots per head, time-shared)
#define POOLN 32768

// workspace byte offsets
#define WS_WQT 0          // u16 wqTf[48][8][64][8]            = 393216
#define WS_WOT 393216     // u16 woTf[16][8][64][8]            = 131072
#define WS_BIAS 524288    // float biasf[8][16][64][4]         = 131072
#define WS_MKG 655360     // float mkg[64][16][64][4]          = 1048576  (frag-ordered mask)

__device__ __forceinline__ u16 f2bf(float f) {
  unsigned u = __float_as_uint(f);
  return (u16)((u + 0x7fffu + ((u >> 16) & 1u)) >> 16);
}
__device__ __forceinline__ unsigned packbf(float a, float b) {
  return (unsigned)f2bf(a) | ((unsigned)f2bf(b) << 16);
}

// Cross-lane fragment assembly (R7-verified pattern).
// Target lane (lo,hi), word wd: value = pack_c[hi>>1][wd&1] from lane lo+16*(2(hi&1)+(wd>>1)).
__device__ __forceinline__ short8 asm_frag(unsigned c0p0, unsigned c0p1,
                                           unsigned c1p0, unsigned c1p1,
                                           int srcA, int srcB, bool cSel) {
  unsigned a0 = (unsigned)__shfl((int)c0p0, srcA);
  unsigned b0 = (unsigned)__shfl((int)c1p0, srcA);
  unsigned a1 = (unsigned)__shfl((int)c0p1, srcA);
  unsigned b1 = (unsigned)__shfl((int)c1p1, srcA);
  unsigned a2 = (unsigned)__shfl((int)c0p0, srcB);
  unsigned b2 = (unsigned)__shfl((int)c1p0, srcB);
  unsigned a3 = (unsigned)__shfl((int)c0p1, srcB);
  unsigned b3 = (unsigned)__shfl((int)c1p1, srcB);
  union { unsigned u[4]; short8 s8; } r;
  r.u[0] = cSel ? b0 : a0;
  r.u[1] = cSel ? b1 : a1;
  r.u[2] = cSel ? b2 : a2;
  r.u[3] = cSel ? b3 : a3;
  return r.s8;
}

// ---------------- prep: frag-order weights (bf16), bias table, mask table ----------------
__global__ void prep_kernel(const float* __restrict__ w_qkv,
                            const float* __restrict__ w_out,
                            const float* __restrict__ rel,
                            const float* __restrict__ mask,
                            u16* __restrict__ wqTf,
                            u16* __restrict__ woTf,
                            float* __restrict__ biasf,
                            float* __restrict__ mkg) {
  const int stride = gridDim.x * blockDim.x;
  const int gid = blockIdx.x * blockDim.x + threadIdx.x;
  for (int e = gid; e < 48 * 8 * 64 * 8; e += stride) {
    int eL = e & 7, ln = (e >> 3) & 63, ks = (e >> 9) & 7, ctg = e >> 12;
    int k = ks * 32 + (ln >> 4) * 8 + eL;
    int c = ctg * 16 + (ln & 15);
    wqTf[e] = f2bf(w_qkv[k * 768 + c]);
  }
  for (int e = gid; e < 16 * 8 * 64 * 8; e += stride) {
    int eL = e & 7, ln = (e >> 3) & 63, ks = (e >> 9) & 7, ctg = e >> 12;
    int k = ks * 32 + (ln >> 4) * 8 + eL;
    int c = ctg * 16 + (ln & 15);
    woTf[e] = f2bf(w_out[k * 256 + c]);
  }
  // biasf[h][t=it*4+jt][lane][rg]: i = it*16+lo, j = jt*16+hi*4+rg; -1e30 for j>=49
  for (int e = gid; e < 8 * 16 * 64 * 4; e += stride) {
    int rg = e & 3, ln = (e >> 2) & 63, t = (e >> 8) & 15, hh = e >> 12;
    int i = (t >> 2) * 16 + (ln & 15);
    int j = (t & 3) * 16 + (ln >> 4) * 4 + rg;
    float v;
    if (j >= NTOK) v = -1e30f;
    else if (i >= NTOK) v = 0.f;
    else {
      int dh = i / 7 - j / 7 + 6;
      int dw = i % 7 - j % 7 + 6;
      v = rel[(dh * 13 + dw) * 8 + hh];
    }
    biasf[e] = v;
  }
  // mkg[wdw][t][lane][rg]: frag-ordered mask per window
  for (int e = gid; e < 64 * 16 * 64 * 4; e += stride) {
    int rg = e & 3, ln = (e >> 2) & 63, t = (e >> 8) & 15, wdw = e >> 12;
    int i = (t >> 2) * 16 + (ln & 15);
    int j = (t & 3) * 16 + (ln >> 4) * 4 + rg;
    mkg[e] = (i < NTOK && j < NTOK) ? mask[wdw * (NTOK * NTOK) + i * NTOK + j] : 0.f;
  }
}

// ---------------- fused window attention: 8 waves, wave = head ----------------
__global__ void __launch_bounds__(512, 4) winattn_mfma(
    const float* __restrict__ x,
    const float* __restrict__ b_qkv,
    const float* __restrict__ b_out,
    const u16* __restrict__ wqTf,
    const u16* __restrict__ woTf,
    const float* __restrict__ biasf,
    const float* __restrict__ mkg,
    float* __restrict__ out)
{
  __shared__ u16 pool[POOLN];
  const int b = blockIdx.x, tid = threadIdx.x;
  const int lane = tid & 63, lo = lane & 15, hi = lane >> 4;
  const int h = tid >> 6;                    // wave id = head id, 0..7
  const f32x4 zf = {0.f, 0.f, 0.f, 0.f};

  // ---- stage: x -> frag order (bf16) ----
  {
    const float4* xg = (const float4*)(x + (size_t)b * (NTOK * 256));
    for (int e = tid; e < 49 * 64; e += 512) {
      float4 v = xg[e];
      int r = e >> 6, c4 = (e & 63) << 2;
      int addr = (((r >> 4) * 8 + (c4 >> 5)) * 64 + ((c4 >> 3) & 3) * 16 + (r & 15)) * 8 + (c4 & 7);
      *(uint2*)&pool[XF + addr] = make_uint2(packbf(v.x, v.y), packbf(v.z, v.w));
    }
    for (int e = tid; e < 15 * 64; e += 512) {   // zero-pad tokens 49..63
      int r = 49 + (e >> 6), c4 = (e & 63) << 2;
      int addr = (((r >> 4) * 8 + (c4 >> 5)) * 64 + ((c4 >> 3) & 3) * 16 + (r & 15)) * 8 + (c4 & 7);
      *(uint2*)&pool[XF + addr] = make_uint2(0u, 0u);
    }
  }
  __syncthreads();   // (a) xf ready

  // ---- phase 1: QKV GEMM for head h, two passes of 3 ctg tiles ----
  // ctgs: q: 2h, 2h+1 | k: 16+2h, 17+2h | v: 32+2h, 33+2h
  unsigned pq[2][4][2], pk[2][4][2];
  {
    const int ctgA[3] = {2 * h, 2 * h + 1, 16 + 2 * h};
    f32x4 acc[3][4];
    #pragma unroll
    for (int ct = 0; ct < 3; ++ct)
      #pragma unroll
      for (int rt = 0; rt < 4; ++rt) acc[ct][rt] = zf;
    #pragma unroll
    for (int ks = 0; ks < 8; ++ks) {
      short8 bx[4];
      #pragma unroll
      for (int rt = 0; rt < 4; ++rt)
        bx[rt] = *(const short8*)&pool[XF + ((rt * 8 + ks) * 64 + lane) * 8];
      #pragma unroll
      for (int ct = 0; ct < 3; ++ct) {
        short8 af = *(const short8*)&wqTf[((size_t)(ctgA[ct] * 8 + ks) * 64 + lane) * 8];
        #pragma unroll
        for (int rt = 0; rt < 4; ++rt)
          acc[ct][rt] = __builtin_amdgcn_mfma_f32_16x16x32_bf16(af, bx[rt], acc[ct][rt], 0, 0, 0);
      }
    }
    #pragma unroll
    for (int ct = 0; ct < 3; ++ct) {
      f32x4 bias = *(const f32x4*)(b_qkv + ctgA[ct] * 16 + hi * 4);
      #pragma unroll
      for (int rt = 0; rt < 4; ++rt) {
        f32x4 v = acc[ct][rt] + bias;
        if (ct < 2) { pq[ct][rt][0] = packbf(v[0], v[1]); pq[ct][rt][1] = packbf(v[2], v[3]); }
        else        { pk[0][rt][0]  = packbf(v[0], v[1]); pk[0][rt][1]  = packbf(v[2], v[3]); }
      }
    }
  }
  {
    const int ctgB[3] = {17 + 2 * h, 32 + 2 * h, 33 + 2 * h};
    f32x4 acc[3][4];
    #pragma unroll
    for (int ct = 0; ct < 3; ++ct)
      #pragma unroll
      for (int rt = 0; rt < 4; ++rt) acc[ct][rt] = zf;
    #pragma unroll
    for (int ks = 0; ks < 8; ++ks) {
      short8 bx[4];
      #pragma unroll
      for (int rt = 0; rt < 4; ++rt)
        bx[rt] = *(const short8*)&pool[XF + ((rt * 8 + ks) * 64 + lane) * 8];
      #pragma unroll
      for (int ct = 0; ct < 3; ++ct) {
        short8 af = *(const short8*)&wqTf[((size_t)(ctgB[ct] * 8 + ks) * 64 + lane) * 8];
        #pragma unroll
        for (int rt = 0; rt < 4; ++rt)
          acc[ct][rt] = __builtin_amdgcn_mfma_f32_16x16x32_bf16(af, bx[rt], acc[ct][rt], 0, 0, 0);
      }
    }
    #pragma unroll
    for (int ct = 0; ct < 3; ++ct) {
      f32x4 bias = *(const f32x4*)(b_qkv + ctgB[ct] * 16 + hi * 4);
      #pragma unroll
      for (int rt = 0; rt < 4; ++rt) {
        f32x4 v = acc[ct][rt] + bias;
        if (ct == 0) { pk[1][rt][0] = packbf(v[0], v[1]); pk[1][rt][1] = packbf(v[2], v[3]); }
        else {
          // v scatter into VY slot (dblk*2+k2)*8 + h  (wave-local)
          const int dblk = ct - 1;
          int k2 = rt >> 1;
          int hi2 = (rt & 1) * 2 + (lo >> 3);
          int e2 = lo & 7;
          int vb = VY + ((dblk * 2 + k2) * 8 + h) * 512 + (hi2 * 16) * 8 + e2;
          pool[vb + (hi * 4 + 0) * 8] = f2bf(v[0]);
          pool[vb + (hi * 4 + 1) * 8] = f2bf(v[1]);
          pool[vb + (hi * 4 + 2) * 8] = f2bf(v[2]);
          pool[vb + (hi * 4 + 3) * 8] = f2bf(v[3]);
        }
      }
    }
  }

  // ---- phase 2+3: QK^T + softmax, all in registers ----
  const int srcA = lo + 32 * (hi & 1);
  const int srcB = srcA + 16;
  const bool cSel = hi >= 2;
  unsigned pkp[4][4][2];
  float rs[4] = {0.f, 0.f, 0.f, 0.f};
  {
    short8 ka[4];
    #pragma unroll
    for (int it = 0; it < 4; ++it)
      ka[it] = asm_frag(pk[0][it][0], pk[0][it][1], pk[1][it][0], pk[1][it][1], srcA, srcB, cSel);
    const float* bh = biasf + h * 4096;
    const float* mh = mkg + (size_t)(b & 63) * 4096;
    #pragma unroll
    for (int jt = 0; jt < 4; ++jt) {
      short8 qa = asm_frag(pq[0][jt][0], pq[0][jt][1], pq[1][jt][0], pq[1][jt][1], srcA, srcB, cSel);
      #pragma unroll
      for (int it = 0; it < 4; ++it) {
        f32x4 st = __builtin_amdgcn_mfma_f32_16x16x32_bf16(qa, ka[it], zf, 0, 0, 0);
        const int t = it * 4 + jt;
        f32x4 bm = *(const f32x4*)&bh[(t * 64 + lane) * 4];
        f32x4 mm = *(const f32x4*)&mh[(t * 64 + lane) * 4];
        float p0 = __expf(fmaf(st[0], 0.17677669529663687f, bm[0] + mm[0]));
        float p1 = __expf(fmaf(st[1], 0.17677669529663687f, bm[1] + mm[1]));
        float p2 = __expf(fmaf(st[2], 0.17677669529663687f, bm[2] + mm[2]));
        float p3 = __expf(fmaf(st[3], 0.17677669529663687f, bm[3] + mm[3]));
        rs[it] += (p0 + p1) + (p2 + p3);
        pkp[jt][it][0] = packbf(p0, p1);
        pkp[jt][it][1] = packbf(p2, p3);
      }
    }
  }
  float inv[4];
  #pragma unroll
  for (int it = 0; it < 4; ++it) {
    float r2 = rs[it] + __shfl_xor(rs[it], 16);
    inv[it] = 1.f / (r2 + __shfl_xor(r2, 32));
  }

  // ---- phase 4: PV; y overwrites the (wave-local) v slots ----
  {
    short8 va[2][2];
    #pragma unroll
    for (int dblk = 0; dblk < 2; ++dblk)
      #pragma unroll
      for (int k2 = 0; k2 < 2; ++k2)
        va[dblk][k2] = *(const short8*)&pool[VY + ((dblk * 2 + k2) * 8 + h) * 512 + lane * 8];
    #pragma unroll
    for (int it = 0; it < 4; ++it) {
      f32x4 y0 = zf, y1 = zf;
      #pragma unroll
      for (int k2 = 0; k2 < 2; ++k2) {
        short8 pb = asm_frag(pkp[2 * k2][it][0], pkp[2 * k2][it][1],
                             pkp[2 * k2 + 1][it][0], pkp[2 * k2 + 1][it][1], srcA, srcB, cSel);
        y0 = __builtin_amdgcn_mfma_f32_16x16x32_bf16(va[0][k2], pb, y0, 0, 0, 0);
        y1 = __builtin_amdgcn_mfma_f32_16x16x32_bf16(va[1][k2], pb, y1, 0, 0, 0);
      }
      const float iv = inv[it];
      #pragma unroll
      for (int dblk = 0; dblk < 2; ++dblk) {
        f32x4 yy = dblk ? y1 : y0;
        int hi2 = dblk * 2 + (hi >> 1);
        int eb = (hi & 1) * 4;
        *(uint2*)&pool[VY + (it * 8 + h) * 512 + (hi2 * 16 + lo) * 8 + eb] =
            make_uint2(packbf(yy[0] * iv, yy[1] * iv), packbf(yy[2] * iv, yy[3] * iv));
      }
    }
  }
  __syncthreads();   // (c) all y frags visible

  // ---- phase 5: output projection, 2 ctg per wave ----
  {
    f32x4 pacc[2][4];
    #pragma unroll
    for (int ct = 0; ct < 2; ++ct)
      #pragma unroll
      for (int rt = 0; rt < 4; ++rt) pacc[ct][rt] = zf;
    #pragma unroll
    for (int ks = 0; ks < 8; ++ks) {
      short8 yb[4];
      #pragma unroll
      for (int rt = 0; rt < 4; ++rt)
        yb[rt] = *(const short8*)&pool[VY + (rt * 8 + ks) * 512 + lane * 8];
      #pragma unroll
      for (int ct = 0; ct < 2; ++ct) {
        short8 wf = *(const short8*)&woTf[((size_t)((h * 2 + ct) * 8 + ks) * 64 + lane) * 8];
        #pragma unroll
        for (int rt = 0; rt < 4; ++rt)
          pacc[ct][rt] = __builtin_amdgcn_mfma_f32_16x16x32_bf16(wf, yb[rt], pacc[ct][rt], 0, 0, 0);
      }
    }
    float* og = out + (size_t)b * (NTOK * 256);
    #pragma unroll
    for (int ct = 0; ct < 2; ++ct) {
      const int cb = (h * 2 + ct) * 16 + hi * 4;
      f32x4 bb = *(const f32x4*)(b_out + cb);
      #pragma unroll
      for (int rt = 0; rt < 4; ++rt) {
        const int r = rt * 16 + lo;
        if (r < NTOK) {
          f32x4 vv = pacc[ct][rt] + bb;
          *(f32x4*)(og + (size_t)r * 256 + cb) = vv;
        }
      }
    }
  }
}

extern "C" void kernel_launch(void* const* d_in, const int* in_sizes, int n_in,
                              void* d_out, int out_size, void* d_ws, size_t ws_size,
                              hipStream_t stream) {
  const float *x = nullptr, *mask = nullptr, *w_qkv = nullptr, *b_qkv = nullptr,
              *rel_t = nullptr, *w_out = nullptr, *b_out = nullptr;
  for (int i = 0; i < n_in; ++i) {
    const float* p = (const float*)d_in[i];
    switch (in_sizes[i]) {
      case 4096 * 49 * 256: x = p; break;
      case 64 * 49 * 49:    mask = p; break;
      case 256 * 768:       w_qkv = p; break;
      case 768:             b_qkv = p; break;
      case 169 * 8:         rel_t = p; break;
      case 256 * 256:       w_out = p; break;
      case 256:             b_out = p; break;
    }
  }
  char* wsb = (char*)d_ws;
  u16* wqTf   = (u16*)(wsb + WS_WQT);
  u16* woTf   = (u16*)(wsb + WS_WOT);
  float* biasf = (float*)(wsb + WS_BIAS);
  float* mkg   = (float*)(wsb + WS_MKG);

  hipLaunchKernelGGL(prep_kernel, dim3(1024), dim3(256), 0, stream,
                     w_qkv, w_out, rel_t, mask, wqTf, woTf, biasf, mkg);
  hipLaunchKernelGGL(winattn_mfma, dim3(NBLK), dim3(512), 0, stream,
                     x, b_qkv, b_out, wqTf, woTf, biasf, mkg, (float*)d_out);
}

// Round 9
// 335.181 us; speedup vs baseline: 2.4850x; 2.4850x over previous
//
#include <hip/hip_runtime.h>

typedef __attribute__((ext_vector_type(8))) short short8;
typedef __attribute__((ext_vector_type(4))) float f32x4;
typedef unsigned short u16;

#define NTOK 49
#define NBLK 4096

// LDS pool (u16 units), 64 KB total -> 2 blocks/CU
#define XF 0        // x frags [rt4][ks8][64][8] = 16384 u16 (32 KB)
#define VY 16384    // 32 slots x 512 u16 (32 KB): v frag f of head h at slot f*8+h;
                    // y frag (rt, ks=h) at slot rt*8+h  (time-shared, wave-local)
#define POOLN 32768

// workspace byte offsets
#define WS_WQT 0          // u16 wqTf[48][8][64][8]            = 393216
#define WS_WOT 393216     // u16 woTf[16][8][64][8]            = 131072
#define WS_BIAS 524288    // float biasf[8][16][64][4]         = 131072
#define WS_MKG 655360     // float mkg[64][16][64][4]          = 1048576  (frag-ordered mask)

__device__ __forceinline__ u16 f2bf(float f) {
  unsigned u = __float_as_uint(f);
  return (u16)((u + 0x7fffu + ((u >> 16) & 1u)) >> 16);
}
__device__ __forceinline__ unsigned packbf(float a, float b) {
  return (unsigned)f2bf(a) | ((unsigned)f2bf(b) << 16);
}

// Cross-lane fragment assembly (R7/R8-verified pattern).
__device__ __forceinline__ short8 asm_frag(unsigned c0p0, unsigned c0p1,
                                           unsigned c1p0, unsigned c1p1,
                                           int srcA, int srcB, bool cSel) {
  unsigned a0 = (unsigned)__shfl((int)c0p0, srcA);
  unsigned b0 = (unsigned)__shfl((int)c1p0, srcA);
  unsigned a1 = (unsigned)__shfl((int)c0p1, srcA);
  unsigned b1 = (unsigned)__shfl((int)c1p1, srcA);
  unsigned a2 = (unsigned)__shfl((int)c0p0, srcB);
  unsigned b2 = (unsigned)__shfl((int)c1p0, srcB);
  unsigned a3 = (unsigned)__shfl((int)c0p1, srcB);
  unsigned b3 = (unsigned)__shfl((int)c1p1, srcB);
  union { unsigned u[4]; short8 s8; } r;
  r.u[0] = cSel ? b0 : a0;
  r.u[1] = cSel ? b1 : a1;
  r.u[2] = cSel ? b2 : a2;
  r.u[3] = cSel ? b3 : a3;
  return r.s8;
}

// ---------------- prep: frag-order weights (bf16), bias table, mask table ----------------
__global__ void prep_kernel(const float* __restrict__ w_qkv,
                            const float* __restrict__ w_out,
                            const float* __restrict__ rel,
                            const float* __restrict__ mask,
                            u16* __restrict__ wqTf,
                            u16* __restrict__ woTf,
                            float* __restrict__ biasf,
                            float* __restrict__ mkg) {
  const int stride = gridDim.x * blockDim.x;
  const int gid = blockIdx.x * blockDim.x + threadIdx.x;
  for (int e = gid; e < 48 * 8 * 64 * 8; e += stride) {
    int eL = e & 7, ln = (e >> 3) & 63, ks = (e >> 9) & 7, ctg = e >> 12;
    int k = ks * 32 + (ln >> 4) * 8 + eL;
    int c = ctg * 16 + (ln & 15);
    wqTf[e] = f2bf(w_qkv[k * 768 + c]);
  }
  for (int e = gid; e < 16 * 8 * 64 * 8; e += stride) {
    int eL = e & 7, ln = (e >> 3) & 63, ks = (e >> 9) & 7, ctg = e >> 12;
    int k = ks * 32 + (ln >> 4) * 8 + eL;
    int c = ctg * 16 + (ln & 15);
    woTf[e] = f2bf(w_out[k * 256 + c]);
  }
  for (int e = gid; e < 8 * 16 * 64 * 4; e += stride) {
    int rg = e & 3, ln = (e >> 2) & 63, t = (e >> 8) & 15, hh = e >> 12;
    int i = (t >> 2) * 16 + (ln & 15);
    int j = (t & 3) * 16 + (ln >> 4) * 4 + rg;
    float v;
    if (j >= NTOK) v = -1e30f;
    else if (i >= NTOK) v = 0.f;
    else {
      int dh = i / 7 - j / 7 + 6;
      int dw = i % 7 - j % 7 + 6;
      v = rel[(dh * 13 + dw) * 8 + hh];
    }
    biasf[e] = v;
  }
  for (int e = gid; e < 64 * 16 * 64 * 4; e += stride) {
    int rg = e & 3, ln = (e >> 2) & 63, t = (e >> 8) & 15, wdw = e >> 12;
    int i = (t >> 2) * 16 + (ln & 15);
    int j = (t & 3) * 16 + (ln >> 4) * 4 + rg;
    mkg[e] = (i < NTOK && j < NTOK) ? mask[wdw * (NTOK * NTOK) + i * NTOK + j] : 0.f;
  }
}

// ---------------- fused window attention: 8 waves, wave = head ----------------
// __launch_bounds__ 2nd arg is CUDA-style min BLOCKS per CU (empirical: (512,4) -> 64-VGPR cap).
// (512,2): 2 blocks x 8 waves = 16 waves/CU -> 128-VGPR cap, matches 64 KB LDS 2-block residency.
__global__ void __launch_bounds__(512, 2) winattn_mfma(
    const float* __restrict__ x,
    const float* __restrict__ b_qkv,
    const float* __restrict__ b_out,
    const u16* __restrict__ wqTf,
    const u16* __restrict__ woTf,
    const float* __restrict__ biasf,
    const float* __restrict__ mkg,
    float* __restrict__ out)
{
  __shared__ u16 pool[POOLN];
  const int b = blockIdx.x, tid = threadIdx.x;
  const int lane = tid & 63, lo = lane & 15, hi = lane >> 4;
  const int h = tid >> 6;                    // wave id = head id, 0..7
  const f32x4 zf = {0.f, 0.f, 0.f, 0.f};

  // ---- stage: x -> frag order (bf16) ----
  {
    const float4* xg = (const float4*)(x + (size_t)b * (NTOK * 256));
    for (int e = tid; e < 49 * 64; e += 512) {
      float4 v = xg[e];
      int r = e >> 6, c4 = (e & 63) << 2;
      int addr = (((r >> 4) * 8 + (c4 >> 5)) * 64 + ((c4 >> 3) & 3) * 16 + (r & 15)) * 8 + (c4 & 7);
      *(uint2*)&pool[XF + addr] = make_uint2(packbf(v.x, v.y), packbf(v.z, v.w));
    }
    for (int e = tid; e < 15 * 64; e += 512) {   // zero-pad tokens 49..63
      int r = 49 + (e >> 6), c4 = (e & 63) << 2;
      int addr = (((r >> 4) * 8 + (c4 >> 5)) * 64 + ((c4 >> 3) & 3) * 16 + (r & 15)) * 8 + (c4 & 7);
      *(uint2*)&pool[XF + addr] = make_uint2(0u, 0u);
    }
  }
  __syncthreads();   // (a) xf ready

  // ---- phase 1: QKV GEMM for head h, THREE passes of 2 ctg tiles (acc peak 32 regs) ----
  unsigned pq[2][4][2], pk[2][4][2];
  #pragma unroll
  for (int pass = 0; pass < 3; ++pass) {
    const int c0 = (pass == 0) ? 2 * h : (pass == 1 ? 16 + 2 * h : 32 + 2 * h);
    f32x4 acc[2][4];
    #pragma unroll
    for (int ct = 0; ct < 2; ++ct)
      #pragma unroll
      for (int rt = 0; rt < 4; ++rt) acc[ct][rt] = zf;
    #pragma unroll
    for (int ks = 0; ks < 8; ++ks) {
      short8 bx[4];
      #pragma unroll
      for (int rt = 0; rt < 4; ++rt)
        bx[rt] = *(const short8*)&pool[XF + ((rt * 8 + ks) * 64 + lane) * 8];
      #pragma unroll
      for (int ct = 0; ct < 2; ++ct) {
        short8 af = *(const short8*)&wqTf[((size_t)((c0 + ct) * 8 + ks) * 64 + lane) * 8];
        #pragma unroll
        for (int rt = 0; rt < 4; ++rt)
          acc[ct][rt] = __builtin_amdgcn_mfma_f32_16x16x32_bf16(af, bx[rt], acc[ct][rt], 0, 0, 0);
      }
    }
    #pragma unroll
    for (int ct = 0; ct < 2; ++ct) {
      f32x4 bias = *(const f32x4*)(b_qkv + (c0 + ct) * 16 + hi * 4);
      #pragma unroll
      for (int rt = 0; rt < 4; ++rt) {
        f32x4 v = acc[ct][rt] + bias;
        if (pass == 0) {
          pq[ct][rt][0] = packbf(v[0], v[1]); pq[ct][rt][1] = packbf(v[2], v[3]);
        } else if (pass == 1) {
          pk[ct][rt][0] = packbf(v[0], v[1]); pk[ct][rt][1] = packbf(v[2], v[3]);
        } else {
          // v scatter into VY slot (dblk*2+k2)*8 + h  (wave-local)
          const int dblk = ct;
          int k2 = rt >> 1;
          int hi2 = (rt & 1) * 2 + (lo >> 3);
          int e2 = lo & 7;
          int vb = VY + ((dblk * 2 + k2) * 8 + h) * 512 + (hi2 * 16) * 8 + e2;
          pool[vb + (hi * 4 + 0) * 8] = f2bf(v[0]);
          pool[vb + (hi * 4 + 1) * 8] = f2bf(v[1]);
          pool[vb + (hi * 4 + 2) * 8] = f2bf(v[2]);
          pool[vb + (hi * 4 + 3) * 8] = f2bf(v[3]);
        }
      }
    }
  }

  // ---- phase 2+3: QK^T + softmax, all in registers ----
  const int srcA = lo + 32 * (hi & 1);
  const int srcB = srcA + 16;
  const bool cSel = hi >= 2;
  unsigned pkp[4][4][2];
  float rs[4] = {0.f, 0.f, 0.f, 0.f};
  {
    short8 ka[4];
    #pragma unroll
    for (int it = 0; it < 4; ++it)
      ka[it] = asm_frag(pk[0][it][0], pk[0][it][1], pk[1][it][0], pk[1][it][1], srcA, srcB, cSel);
    const float* bh = biasf + h * 4096;
    const float* mh = mkg + (size_t)(b & 63) * 4096;
    #pragma unroll
    for (int jt = 0; jt < 4; ++jt) {
      short8 qa = asm_frag(pq[0][jt][0], pq[0][jt][1], pq[1][jt][0], pq[1][jt][1], srcA, srcB, cSel);
      #pragma unroll
      for (int it = 0; it < 4; ++it) {
        f32x4 st = __builtin_amdgcn_mfma_f32_16x16x32_bf16(qa, ka[it], zf, 0, 0, 0);
        const int t = it * 4 + jt;
        f32x4 bm = *(const f32x4*)&bh[(t * 64 + lane) * 4];
        f32x4 mm = *(const f32x4*)&mh[(t * 64 + lane) * 4];
        float p0 = __expf(fmaf(st[0], 0.17677669529663687f, bm[0] + mm[0]));
        float p1 = __expf(fmaf(st[1], 0.17677669529663687f, bm[1] + mm[1]));
        float p2 = __expf(fmaf(st[2], 0.17677669529663687f, bm[2] + mm[2]));
        float p3 = __expf(fmaf(st[3], 0.17677669529663687f, bm[3] + mm[3]));
        rs[it] += (p0 + p1) + (p2 + p3);
        pkp[jt][it][0] = packbf(p0, p1);
        pkp[jt][it][1] = packbf(p2, p3);
      }
    }
  }
  float inv[4];
  #pragma unroll
  for (int it = 0; it < 4; ++it) {
    float r2 = rs[it] + __shfl_xor(rs[it], 16);
    inv[it] = 1.f / (r2 + __shfl_xor(r2, 32));
  }

  // ---- phase 4: PV; y overwrites the (wave-local) v slots ----
  {
    short8 va[2][2];
    #pragma unroll
    for (int dblk = 0; dblk < 2; ++dblk)
      #pragma unroll
      for (int k2 = 0; k2 < 2; ++k2)
        va[dblk][k2] = *(const short8*)&pool[VY + ((dblk * 2 + k2) * 8 + h) * 512 + lane * 8];
    #pragma unroll
    for (int it = 0; it < 4; ++it) {
      f32x4 y0 = zf, y1 = zf;
      #pragma unroll
      for (int k2 = 0; k2 < 2; ++k2) {
        short8 pb = asm_frag(pkp[2 * k2][it][0], pkp[2 * k2][it][1],
                             pkp[2 * k2 + 1][it][0], pkp[2 * k2 + 1][it][1], srcA, srcB, cSel);
        y0 = __builtin_amdgcn_mfma_f32_16x16x32_bf16(va[0][k2], pb, y0, 0, 0, 0);
        y1 = __builtin_amdgcn_mfma_f32_16x16x32_bf16(va[1][k2], pb, y1, 0, 0, 0);
      }
      const float iv = inv[it];
      #pragma unroll
      for (int dblk = 0; dblk < 2; ++dblk) {
        f32x4 yy = dblk ? y1 : y0;
        int hi2 = dblk * 2 + (hi >> 1);
        int eb = (hi & 1) * 4;
        *(uint2*)&pool[VY + (it * 8 + h) * 512 + (hi2 * 16 + lo) * 8 + eb] =
            make_uint2(packbf(yy[0] * iv, yy[1] * iv), packbf(yy[2] * iv, yy[3] * iv));
      }
    }
  }
  __syncthreads();   // (c) all y frags visible

  // ---- phase 5: output projection, 2 ctg per wave ----
  {
    f32x4 pacc[2][4];
    #pragma unroll
    for (int ct = 0; ct < 2; ++ct)
      #pragma unroll
      for (int rt = 0; rt < 4; ++rt) pacc[ct][rt] = zf;
    #pragma unroll
    for (int ks = 0; ks < 8; ++ks) {
      short8 yb[4];
      #pragma unroll
      for (int rt = 0; rt < 4; ++rt)
        yb[rt] = *(const short8*)&pool[VY + (rt * 8 + ks) * 512 + lane * 8];
      #pragma unroll
      for (int ct = 0; ct < 2; ++ct) {
        short8 wf = *(const short8*)&woTf[((size_t)((h * 2 + ct) * 8 + ks) * 64 + lane) * 8];
        #pragma unroll
        for (int rt = 0; rt < 4; ++rt)
          pacc[ct][rt] = __builtin_amdgcn_mfma_f32_16x16x32_bf16(wf, yb[rt], pacc[ct][rt], 0, 0, 0);
      }
    }
    float* og = out + (size_t)b * (NTOK * 256);
    #pragma unroll
    for (int ct = 0; ct < 2; ++ct) {
      const int cb = (h * 2 + ct) * 16 + hi * 4;
      f32x4 bb = *(const f32x4*)(b_out + cb);
      #pragma unroll
      for (int rt = 0; rt < 4; ++rt) {
        const int r = rt * 16 + lo;
        if (r < NTOK) {
          f32x4 vv = pacc[ct][rt] + bb;
          *(f32x4*)(og + (size_t)r * 256 + cb) = vv;
        }
      }
    }
  }
}

extern "C" void kernel_launch(void* const* d_in, const int* in_sizes, int n_in,
                              void* d_out, int out_size, void* d_ws, size_t ws_size,
                              hipStream_t stream) {
  const float *x = nullptr, *mask = nullptr, *w_qkv = nullptr, *b_qkv = nullptr,
              *rel_t = nullptr, *w_out = nullptr, *b_out = nullptr;
  for (int i = 0; i < n_in; ++i) {
    const float* p = (const float*)d_in[i];
    switch (in_sizes[i]) {
      case 4096 * 49 * 256: x = p; break;
      case 64 * 49 * 49:    mask = p; break;
      case 256 * 768:       w_qkv = p; break;
      case 768:             b_qkv = p; break;
      case 169 * 8:         rel_t = p; break;
      case 256 * 256:       w_out = p; break;
      case 256:             b_out = p; break;
    }
  }
  char* wsb = (char*)d_ws;
  u16* wqTf   = (u16*)(wsb + WS_WQT);
  u16* woTf   = (u16*)(wsb + WS_WOT);
  float* biasf = (float*)(wsb + WS_BIAS);
  float* mkg   = (float*)(wsb + WS_MKG);

  hipLaunchKernelGGL(prep_kernel, dim3(1024), dim3(256), 0, stream,
                     w_qkv, w_out, rel_t, mask, wqTf, woTf, biasf, mkg);
  hipLaunchKernelGGL(winattn_mfma, dim3(NBLK), dim3(512), 0, stream,
                     x, b_qkv, b_out, wqTf, woTf, biasf, mkg, (float*)d_out);
}

// Round 10
// 318.913 us; speedup vs baseline: 2.6117x; 1.0510x over previous
//
#include <hip/hip_runtime.h>

typedef __attribute__((ext_vector_type(8))) short short8;
typedef __attribute__((ext_vector_type(4))) float f32x4;
typedef unsigned short u16;

#define NTOK 49
#define NBLK 4096
#define LOG2E 1.4426950408889634f

// LDS pool (u16 units), 128 KB
#define XF  0       // x frags [rt4][ks8][64][8], XOR-swizzled; later y frags [it4][h8][64][8] linear
#define QKP 16384   // per head 4096 u16: q[4][64][8] | k[4][64][8]
#define VTF 49152   // 32 slots x 512 u16: v^T frag f of head h at slot f*8+h
#define POOLN 65536

// workspace byte offsets
#define WS_WQT 0          // u16 wqTf[48][8][64][8]  = 393216
#define WS_WOT 393216     // u16 woTf[16][8][64][8]  = 131072
#define WS_BIAS 524288    // float biasf[8][16][64][4] = 131072   (pre-scaled by LOG2E)
#define WS_MKG 655360     // float mkg[64][16][64][4]  = 1048576  (pre-scaled by LOG2E)

__device__ __forceinline__ u16 f2bf(float f) {
  unsigned u = __float_as_uint(f);
  return (u16)((u + 0x7fffu + ((u >> 16) & 1u)) >> 16);
}
__device__ __forceinline__ unsigned packbf(float a, float b) {
  return (unsigned)f2bf(a) | ((unsigned)f2bf(b) << 16);
}

// Cross-lane fragment assembly (R7-verified).
__device__ __forceinline__ short8 asm_frag(unsigned c0p0, unsigned c0p1,
                                           unsigned c1p0, unsigned c1p1,
                                           int srcA, int srcB, bool cSel) {
  unsigned a0 = (unsigned)__shfl((int)c0p0, srcA);
  unsigned b0 = (unsigned)__shfl((int)c1p0, srcA);
  unsigned a1 = (unsigned)__shfl((int)c0p1, srcA);
  unsigned b1 = (unsigned)__shfl((int)c1p1, srcA);
  unsigned a2 = (unsigned)__shfl((int)c0p0, srcB);
  unsigned b2 = (unsigned)__shfl((int)c1p0, srcB);
  unsigned a3 = (unsigned)__shfl((int)c0p1, srcB);
  unsigned b3 = (unsigned)__shfl((int)c1p1, srcB);
  union { unsigned u[4]; short8 s8; } r;
  r.u[0] = cSel ? b0 : a0;
  r.u[1] = cSel ? b1 : a1;
  r.u[2] = cSel ? b2 : a2;
  r.u[3] = cSel ? b3 : a3;
  return r.s8;
}

// ---------------- prep: frag-order weights (bf16), scaled bias + mask tables ----------------
__global__ void prep_kernel(const float* __restrict__ w_qkv,
                            const float* __restrict__ w_out,
                            const float* __restrict__ rel,
                            const float* __restrict__ mask,
                            u16* __restrict__ wqTf,
                            u16* __restrict__ woTf,
                            float* __restrict__ biasf,
                            float* __restrict__ mkg) {
  const int stride = gridDim.x * blockDim.x;
  const int gid = blockIdx.x * blockDim.x + threadIdx.x;
  for (int e = gid; e < 48 * 8 * 64 * 8; e += stride) {
    int eL = e & 7, ln = (e >> 3) & 63, ks = (e >> 9) & 7, ctg = e >> 12;
    int k = ks * 32 + (ln >> 4) * 8 + eL;
    int c = ctg * 16 + (ln & 15);
    wqTf[e] = f2bf(w_qkv[k * 768 + c]);
  }
  for (int e = gid; e < 16 * 8 * 64 * 8; e += stride) {
    int eL = e & 7, ln = (e >> 3) & 63, ks = (e >> 9) & 7, ctg = e >> 12;
    int k = ks * 32 + (ln >> 4) * 8 + eL;
    int c = ctg * 16 + (ln & 15);
    woTf[e] = f2bf(w_out[k * 256 + c]);
  }
  // biasf[h][t=it*4+jt][lane][rg] * LOG2E: i = it*16+lo, j = jt*16+hi*4+rg
  for (int e = gid; e < 8 * 16 * 64 * 4; e += stride) {
    int rg = e & 3, ln = (e >> 2) & 63, t = (e >> 8) & 15, hh = e >> 12;
    int i = (t >> 2) * 16 + (ln & 15);
    int j = (t & 3) * 16 + (ln >> 4) * 4 + rg;
    float v;
    if (j >= NTOK) v = -1e30f;
    else if (i >= NTOK) v = 0.f;
    else {
      int dh = i / 7 - j / 7 + 6;
      int dw = i % 7 - j % 7 + 6;
      v = rel[(dh * 13 + dw) * 8 + hh];
    }
    biasf[e] = v * LOG2E;
  }
  for (int e = gid; e < 64 * 16 * 64 * 4; e += stride) {
    int rg = e & 3, ln = (e >> 2) & 63, t = (e >> 8) & 15, wdw = e >> 12;
    int i = (t >> 2) * 16 + (ln & 15);
    int j = (t & 3) * 16 + (ln >> 4) * 4 + rg;
    mkg[e] = (i < NTOK && j < NTOK) ? mask[wdw * (NTOK * NTOK) + i * NTOK + j] * LOG2E : 0.f;
  }
}

// ---------------- fused window attention: 16 waves ----------------
__global__ void __launch_bounds__(1024, 4) winattn_mfma(
    const float* __restrict__ x,
    const float* __restrict__ b_qkv,
    const float* __restrict__ b_out,
    const u16* __restrict__ wqTf,
    const u16* __restrict__ woTf,
    const float* __restrict__ biasf,
    const float* __restrict__ mkg,
    float* __restrict__ out)
{
  __shared__ u16 pool[POOLN];
  const int b = blockIdx.x, tid = threadIdx.x;
  const int lane = tid & 63, lo = lane & 15, hi = lane >> 4;
  const int w = tid >> 6;            // 0..15
  const int h = w & 7;               // head (for attention phases)
  const int it0 = (w >> 3) * 2;      // i-tile half: 0 or 2
  const f32x4 zf = {0.f, 0.f, 0.f, 0.f};

  // ---- stage: x -> XOR-swizzled frag order (write conflict-free, read conflict-free) ----
  {
    const float4* xg = (const float4*)(x + (size_t)b * (NTOK * 256));
    for (int e = tid; e < 49 * 64; e += 1024) {
      float4 v = xg[e];
      int r = e >> 6, ks = (e >> 3) & 7, sub = (e >> 1) & 3, eb = (e & 1) * 4;
      int unit = ((r >> 4) * 8 + ks) * 64 + sub * 16 + ((r & 15) ^ ((2 * sub + ks) & 15));
      *(uint2*)&pool[XF + unit * 8 + eb] = make_uint2(packbf(v.x, v.y), packbf(v.z, v.w));
    }
    if (tid < 15 * 64) {   // zero-pad tokens 49..63
      int e = tid;
      int r = 49 + (e >> 6), c = e & 63;
      int ks = c >> 3, sub = (c >> 1) & 3, eb = (c & 1) * 4;
      int unit = ((r >> 4) * 8 + ks) * 64 + sub * 16 + ((r & 15) ^ ((2 * sub + ks) & 15));
      *(uint2*)&pool[XF + unit * 8 + eb] = make_uint2(0u, 0u);
    }
  }
  __syncthreads();   // (a) xf ready

  // ---- phase 1: QKV GEMM. wave w: q/k ctgs {2w, 2w+1}, v ctg 32+w (swapped-operand) ----
  {
    const int ctq0 = 2 * w, ctq1 = 2 * w + 1, ctv = 32 + w;
    f32x4 acc[3][4];
    #pragma unroll
    for (int ct = 0; ct < 3; ++ct)
      #pragma unroll
      for (int rt = 0; rt < 4; ++rt) acc[ct][rt] = zf;
    const int lo2 = 2 * hi;   // for read-side swizzle
    #pragma unroll
    for (int ks = 0; ks < 8; ++ks) {
      const int swz = (lo ^ ((lo2 + ks) & 15));
      short8 bx[4];
      #pragma unroll
      for (int rt = 0; rt < 4; ++rt)
        bx[rt] = *(const short8*)&pool[XF + (((rt * 8 + ks) * 64) + hi * 16 + swz) * 8];
      short8 af0 = *(const short8*)&wqTf[((size_t)(ctq0 * 8 + ks) * 64 + lane) * 8];
      short8 af1 = *(const short8*)&wqTf[((size_t)(ctq1 * 8 + ks) * 64 + lane) * 8];
      short8 afv = *(const short8*)&wqTf[((size_t)(ctv * 8 + ks) * 64 + lane) * 8];
      #pragma unroll
      for (int rt = 0; rt < 4; ++rt) {
        acc[0][rt] = __builtin_amdgcn_mfma_f32_16x16x32_bf16(af0, bx[rt], acc[0][rt], 0, 0, 0);
        acc[1][rt] = __builtin_amdgcn_mfma_f32_16x16x32_bf16(af1, bx[rt], acc[1][rt], 0, 0, 0);
        acc[2][rt] = __builtin_amdgcn_mfma_f32_16x16x32_bf16(bx[rt], afv, acc[2][rt], 0, 0, 0);
      }
    }
    // epilogue q/k: wave w<8 -> q[head w]; w>=8 -> k[head w-8]
    const int qkbase = QKP + (w & 7) * 4096 + ((w >= 8) ? 2048 : 0);
    #pragma unroll
    for (int ct = 0; ct < 2; ++ct) {
      const int ctg = 2 * w + ct;
      f32x4 bias = *(const f32x4*)(b_qkv + ctg * 16 + hi * 4);
      #pragma unroll
      for (int rt = 0; rt < 4; ++rt) {
        f32x4 v = acc[ct][rt] + bias;
        int hi2 = ct * 2 + (hi >> 1);
        int eb = (hi & 1) * 4;
        *(uint2*)&pool[qkbase + (rt * 64 + hi2 * 16 + lo) * 8 + eb] =
            make_uint2(packbf(v[0], v[1]), packbf(v[2], v[3]));
      }
    }
    // epilogue v (swapped D: lane lo = channel, regs = tokens) -> packed b64, no scatter
    {
      const int vhead = w >> 1, dblk = w & 1;
      const float bv = b_qkv[ctv * 16 + lo];
      #pragma unroll
      for (int rt = 0; rt < 4; ++rt) {
        f32x4 v = acc[2][rt];
        float v0 = v[0] + bv, v1 = v[1] + bv, v2 = v[2] + bv, v3 = v[3] + bv;
        int f = dblk * 2 + (rt >> 1);
        int hiR = (rt & 1) * 2 + (hi >> 1);
        int eb = (hi & 1) * 4;
        *(uint2*)&pool[VTF + (f * 8 + vhead) * 512 + (hiR * 16 + lo) * 8 + eb] =
            make_uint2(packbf(v0, v1), packbf(v2, v3));
      }
    }
  }
  __syncthreads();   // (b) q/k/v visible; XF dead (y may overwrite)

  // ---- phase 2+3: S^T tiles (it0..it0+1) + softmax; p stays in registers ----
  float rs0 = 0.f, rs1 = 0.f;
  unsigned pkp[4][2][2];
  {
    const float SC = 0.17677669529663687f * LOG2E;
    short8 ka0 = *(const short8*)&pool[QKP + h * 4096 + 2048 + ((it0 + 0) * 64 + lane) * 8];
    short8 ka1 = *(const short8*)&pool[QKP + h * 4096 + 2048 + ((it0 + 1) * 64 + lane) * 8];
    const float* bh = biasf + h * 4096;
    const float* mh = mkg + (size_t)(b & 63) * 4096;
    #pragma unroll
    for (int jt = 0; jt < 4; ++jt) {
      short8 qa = *(const short8*)&pool[QKP + h * 4096 + (jt * 64 + lane) * 8];
      f32x4 s0 = __builtin_amdgcn_mfma_f32_16x16x32_bf16(qa, ka0, zf, 0, 0, 0);
      f32x4 s1 = __builtin_amdgcn_mfma_f32_16x16x32_bf16(qa, ka1, zf, 0, 0, 0);
      {
        const int t = (it0 + 0) * 4 + jt;
        f32x4 bm = *(const f32x4*)&bh[(t * 64 + lane) * 4];
        f32x4 mm = *(const f32x4*)&mh[(t * 64 + lane) * 4];
        float p0 = exp2f(fmaf(s0[0], SC, bm[0] + mm[0]));
        float p1 = exp2f(fmaf(s0[1], SC, bm[1] + mm[1]));
        float p2 = exp2f(fmaf(s0[2], SC, bm[2] + mm[2]));
        float p3 = exp2f(fmaf(s0[3], SC, bm[3] + mm[3]));
        rs0 += (p0 + p1) + (p2 + p3);
        pkp[jt][0][0] = packbf(p0, p1);
        pkp[jt][0][1] = packbf(p2, p3);
      }
      {
        const int t = (it0 + 1) * 4 + jt;
        f32x4 bm = *(const f32x4*)&bh[(t * 64 + lane) * 4];
        f32x4 mm = *(const f32x4*)&mh[(t * 64 + lane) * 4];
        float p0 = exp2f(fmaf(s1[0], SC, bm[0] + mm[0]));
        float p1 = exp2f(fmaf(s1[1], SC, bm[1] + mm[1]));
        float p2 = exp2f(fmaf(s1[2], SC, bm[2] + mm[2]));
        float p3 = exp2f(fmaf(s1[3], SC, bm[3] + mm[3]));
        rs1 += (p0 + p1) + (p2 + p3);
        pkp[jt][1][0] = packbf(p0, p1);
        pkp[jt][1][1] = packbf(p2, p3);
      }
    }
  }
  float inv0, inv1;
  {
    float r2 = rs0 + __shfl_xor(rs0, 16);
    inv0 = 1.f / (r2 + __shfl_xor(r2, 32));
    float r3 = rs1 + __shfl_xor(rs1, 16);
    inv1 = 1.f / (r3 + __shfl_xor(r3, 32));
  }

  // ---- phase 4: PV; pb assembled via shfl; y frags -> XF (linear) ----
  {
    const int srcA = lo + 32 * (hi & 1);
    const int srcB = srcA + 16;
    const bool cSel = (hi & 2) != 0;
    short8 va[2][2];
    #pragma unroll
    for (int dblk = 0; dblk < 2; ++dblk)
      #pragma unroll
      for (int k2 = 0; k2 < 2; ++k2)
        va[dblk][k2] = *(const short8*)&pool[VTF + ((dblk * 2 + k2) * 8 + h) * 512 + lane * 8];
    f32x4 ya[2][2];
    ya[0][0] = zf; ya[0][1] = zf; ya[1][0] = zf; ya[1][1] = zf;
    #pragma unroll
    for (int itL = 0; itL < 2; ++itL)
      #pragma unroll
      for (int k2 = 0; k2 < 2; ++k2) {
        short8 pb = asm_frag(pkp[2 * k2][itL][0], pkp[2 * k2][itL][1],
                             pkp[2 * k2 + 1][itL][0], pkp[2 * k2 + 1][itL][1], srcA, srcB, cSel);
        ya[0][itL] = __builtin_amdgcn_mfma_f32_16x16x32_bf16(va[0][k2], pb, ya[0][itL], 0, 0, 0);
        ya[1][itL] = __builtin_amdgcn_mfma_f32_16x16x32_bf16(va[1][k2], pb, ya[1][itL], 0, 0, 0);
      }
    #pragma unroll
    for (int itL = 0; itL < 2; ++itL) {
      const float iv = itL ? inv1 : inv0;
      #pragma unroll
      for (int dblk = 0; dblk < 2; ++dblk) {
        f32x4 yy = ya[dblk][itL];
        int hi2 = dblk * 2 + (hi >> 1);
        int eb = (hi & 1) * 4;
        *(uint2*)&pool[XF + (((it0 + itL) * 8 + h) * 64 + hi2 * 16 + lo) * 8 + eb] =
            make_uint2(packbf(yy[0] * iv, yy[1] * iv), packbf(yy[2] * iv, yy[3] * iv));
      }
    }
  }
  __syncthreads();   // (c) y frags ready

  // ---- phase 5: output projection, 1 ctg per wave ----
  {
    f32x4 pacc[4];
    pacc[0] = zf; pacc[1] = zf; pacc[2] = zf; pacc[3] = zf;
    #pragma unroll
    for (int ks = 0; ks < 8; ++ks) {
      short8 wf = *(const short8*)&woTf[((size_t)(w * 8 + ks) * 64 + lane) * 8];
      #pragma unroll
      for (int rt = 0; rt < 4; ++rt) {
        short8 yb = *(const short8*)&pool[XF + ((rt * 8 + ks) * 64 + lane) * 8];
        pacc[rt] = __builtin_amdgcn_mfma_f32_16x16x32_bf16(wf, yb, pacc[rt], 0, 0, 0);
      }
    }
    float* og = out + (size_t)b * (NTOK * 256);
    const int cb = w * 16 + hi * 4;
    f32x4 bb = *(const f32x4*)(b_out + cb);
    #pragma unroll
    for (int rt = 0; rt < 4; ++rt) {
      const int r = rt * 16 + lo;
      if (r < NTOK) {
        f32x4 vv = pacc[rt] + bb;
        *(f32x4*)(og + (size_t)r * 256 + cb) = vv;
      }
    }
  }
}

extern "C" void kernel_launch(void* const* d_in, const int* in_sizes, int n_in,
                              void* d_out, int out_size, void* d_ws, size_t ws_size,
                              hipStream_t stream) {
  const float *x = nullptr, *mask = nullptr, *w_qkv = nullptr, *b_qkv = nullptr,
              *rel_t = nullptr, *w_out = nullptr, *b_out = nullptr;
  for (int i = 0; i < n_in; ++i) {
    const float* p = (const float*)d_in[i];
    switch (in_sizes[i]) {
      case 4096 * 49 * 256: x = p; break;
      case 64 * 49 * 49:    mask = p; break;
      case 256 * 768:       w_qkv = p; break;
      case 768:             b_qkv = p; break;
      case 169 * 8:         rel_t = p; break;
      case 256 * 256:       w_out = p; break;
      case 256:             b_out = p; break;
    }
  }
  char* wsb = (char*)d_ws;
  u16* wqTf    = (u16*)(wsb + WS_WQT);
  u16* woTf    = (u16*)(wsb + WS_WOT);
  float* biasf = (float*)(wsb + WS_BIAS);
  float* mkg   = (float*)(wsb + WS_MKG);

  hipLaunchKernelGGL(prep_kernel, dim3(1024), dim3(256), 0, stream,
                     w_qkv, w_out, rel_t, mask, wqTf, woTf, biasf, mkg);
  hipLaunchKernelGGL(winattn_mfma, dim3(NBLK), dim3(1024), 0, stream,
                     x, b_qkv, b_out, wqTf, woTf, biasf, mkg, (float*)d_out);
}

// Round 11
// 301.748 us; speedup vs baseline: 2.7603x; 1.0569x over previous
//
#include <hip/hip_runtime.h>

typedef __attribute__((ext_vector_type(8))) short short8;
typedef __attribute__((ext_vector_type(4))) float f32x4;
typedef unsigned short u16;

#define NTOK 49
#define NBLK 4096
#define LOG2E 1.4426950408889634f

// LDS pool (u16 units)
#define XF  0       // x frags [rt4][ks8][64][8] linear; later y frags [it4][h8][64][8]
#define QKP 16384   // per head 4096 u16: q[4][64][8] | k[4][64][8]
#define VTF 49152   // 32 slots x 512 u16: v^T frag f of head h at slot f*8+h
#define MKF 65536   // float[16][64][4] mask frags (8192 u16), LOG2E-prescaled
#define POOLN 73728 // 147456 B

// workspace byte offsets
#define WS_WQT 0          // u16 wqTf[48][8][64][8]    = 393216
#define WS_WOT 393216     // u16 woTf[16][8][64][8]    = 131072
#define WS_BIAS 524288    // float biasf[8][16][64][4] = 131072   (x LOG2E)
#define WS_MKG 655360     // float mkg[64][16][64][4]  = 1048576  (x LOG2E)

__device__ __forceinline__ u16 f2bf(float f) {
  unsigned u = __float_as_uint(f);
  return (u16)((u + 0x7fffu + ((u >> 16) & 1u)) >> 16);
}
// single-instruction packed f32x2 -> bf16x2 (RNE), schedulable (non-volatile)
__device__ __forceinline__ unsigned packbf(float a, float b) {
  unsigned r;
  asm("v_cvt_pk_bf16_f32 %0, %1, %2" : "=v"(r) : "v"(a), "v"(b));
  return r;
}

// Cross-lane fragment assembly (R7-verified).
__device__ __forceinline__ short8 asm_frag(unsigned c0p0, unsigned c0p1,
                                           unsigned c1p0, unsigned c1p1,
                                           int srcA, int srcB, bool cSel) {
  unsigned a0 = (unsigned)__shfl((int)c0p0, srcA);
  unsigned b0 = (unsigned)__shfl((int)c1p0, srcA);
  unsigned a1 = (unsigned)__shfl((int)c0p1, srcA);
  unsigned b1 = (unsigned)__shfl((int)c1p1, srcA);
  unsigned a2 = (unsigned)__shfl((int)c0p0, srcB);
  unsigned b2 = (unsigned)__shfl((int)c1p0, srcB);
  unsigned a3 = (unsigned)__shfl((int)c0p1, srcB);
  unsigned b3 = (unsigned)__shfl((int)c1p1, srcB);
  union { unsigned u[4]; short8 s8; } r;
  r.u[0] = cSel ? b0 : a0;
  r.u[1] = cSel ? b1 : a1;
  r.u[2] = cSel ? b2 : a2;
  r.u[3] = cSel ? b3 : a3;
  return r.s8;
}

// ---------------- prep: frag-order weights (bf16), scaled bias + mask tables ----------------
__global__ void prep_kernel(const float* __restrict__ w_qkv,
                            const float* __restrict__ w_out,
                            const float* __restrict__ rel,
                            const float* __restrict__ mask,
                            u16* __restrict__ wqTf,
                            u16* __restrict__ woTf,
                            float* __restrict__ biasf,
                            float* __restrict__ mkg) {
  const int stride = gridDim.x * blockDim.x;
  const int gid = blockIdx.x * blockDim.x + threadIdx.x;
  for (int e = gid; e < 48 * 8 * 64 * 8; e += stride) {
    int eL = e & 7, ln = (e >> 3) & 63, ks = (e >> 9) & 7, ctg = e >> 12;
    int k = ks * 32 + (ln >> 4) * 8 + eL;
    int c = ctg * 16 + (ln & 15);
    wqTf[e] = f2bf(w_qkv[k * 768 + c]);
  }
  for (int e = gid; e < 16 * 8 * 64 * 8; e += stride) {
    int eL = e & 7, ln = (e >> 3) & 63, ks = (e >> 9) & 7, ctg = e >> 12;
    int k = ks * 32 + (ln >> 4) * 8 + eL;
    int c = ctg * 16 + (ln & 15);
    woTf[e] = f2bf(w_out[k * 256 + c]);
  }
  // biasf[h][t=it*4+jt][lane][rg] * LOG2E: i = it*16+lo, j = jt*16+hi*4+rg
  for (int e = gid; e < 8 * 16 * 64 * 4; e += stride) {
    int rg = e & 3, ln = (e >> 2) & 63, t = (e >> 8) & 15, hh = e >> 12;
    int i = (t >> 2) * 16 + (ln & 15);
    int j = (t & 3) * 16 + (ln >> 4) * 4 + rg;
    float v;
    if (j >= NTOK) v = -1e30f;
    else if (i >= NTOK) v = 0.f;
    else {
      int dh = i / 7 - j / 7 + 6;
      int dw = i % 7 - j % 7 + 6;
      v = rel[(dh * 13 + dw) * 8 + hh];
    }
    biasf[e] = v * LOG2E;
  }
  for (int e = gid; e < 64 * 16 * 64 * 4; e += stride) {
    int rg = e & 3, ln = (e >> 2) & 63, t = (e >> 8) & 15, wdw = e >> 12;
    int i = (t >> 2) * 16 + (ln & 15);
    int j = (t & 3) * 16 + (ln >> 4) * 4 + rg;
    mkg[e] = (i < NTOK && j < NTOK) ? mask[wdw * (NTOK * NTOK) + i * NTOK + j] * LOG2E : 0.f;
  }
}

// ---------------- fused window attention: 16 waves ----------------
__global__ void __launch_bounds__(1024, 4) winattn_mfma(
    const float* __restrict__ x,
    const float* __restrict__ b_qkv,
    const float* __restrict__ b_out,
    const u16* __restrict__ wqTf,
    const u16* __restrict__ woTf,
    const float* __restrict__ biasf,
    const float* __restrict__ mkg,
    float* __restrict__ out)
{
  __shared__ u16 pool[POOLN];
  const int b = blockIdx.x, tid = threadIdx.x;
  const int lane = tid & 63, lo = lane & 15, hi = lane >> 4;
  const int w = tid >> 6;            // 0..15
  const int h = w & 7;               // head (attention phases)
  const int it0 = (w >> 3) * 2;      // i-tile half: 0 or 2
  const f32x4 zf = {0.f, 0.f, 0.f, 0.f};
  float* mkf = (float*)(pool + MKF);

  // ---- stage: x -> linear frag order; mask table -> LDS (straight copy) ----
  {
    const float4* xg = (const float4*)(x + (size_t)b * (NTOK * 256));
    for (int e = tid; e < 49 * 64; e += 1024) {
      float4 v = xg[e];
      int r = e >> 6, c4 = (e & 63) << 2;
      int addr = (((r >> 4) * 8 + (c4 >> 5)) * 64 + ((c4 >> 3) & 3) * 16 + (r & 15)) * 8 + (c4 & 7);
      *(uint2*)&pool[XF + addr] = make_uint2(packbf(v.x, v.y), packbf(v.z, v.w));
    }
    if (tid < 15 * 64) {   // zero-pad tokens 49..63
      int e = tid;
      int r = 49 + (e >> 6), c4 = (e & 63) << 2;
      int addr = (((r >> 4) * 8 + (c4 >> 5)) * 64 + ((c4 >> 3) & 3) * 16 + (r & 15)) * 8 + (c4 & 7);
      *(uint2*)&pool[XF + addr] = make_uint2(0u, 0u);
    }
    const float4* mg = (const float4*)(mkg + (size_t)(b & 63) * 4096);
    for (int e = tid; e < 1024; e += 1024) {
      *(float4*)&mkf[e * 4] = mg[e];
    }
  }
  __syncthreads();   // (a) xf/mkf ready

  // ---- phase 1: QKV GEMM. wave w: q/k ctgs {2w,2w+1}; v ctg 32+w swapped-operand ----
  {
    const int ctq0 = 2 * w, ctq1 = 2 * w + 1, ctv = 32 + w;
    f32x4 acc[3][4];
    #pragma unroll
    for (int ct = 0; ct < 3; ++ct)
      #pragma unroll
      for (int rt = 0; rt < 4; ++rt) acc[ct][rt] = zf;
    #pragma unroll
    for (int ks = 0; ks < 8; ++ks) {
      short8 bx[4];
      #pragma unroll
      for (int rt = 0; rt < 4; ++rt)
        bx[rt] = *(const short8*)&pool[XF + ((rt * 8 + ks) * 64 + lane) * 8];
      short8 af0 = *(const short8*)&wqTf[((size_t)(ctq0 * 8 + ks) * 64 + lane) * 8];
      short8 af1 = *(const short8*)&wqTf[((size_t)(ctq1 * 8 + ks) * 64 + lane) * 8];
      short8 afv = *(const short8*)&wqTf[((size_t)(ctv * 8 + ks) * 64 + lane) * 8];
      #pragma unroll
      for (int rt = 0; rt < 4; ++rt) {
        acc[0][rt] = __builtin_amdgcn_mfma_f32_16x16x32_bf16(af0, bx[rt], acc[0][rt], 0, 0, 0);
        acc[1][rt] = __builtin_amdgcn_mfma_f32_16x16x32_bf16(af1, bx[rt], acc[1][rt], 0, 0, 0);
        acc[2][rt] = __builtin_amdgcn_mfma_f32_16x16x32_bf16(bx[rt], afv, acc[2][rt], 0, 0, 0);
      }
    }
    // epilogue q/k: wave w<8 -> q[head w]; w>=8 -> k[head w-8]
    const int qkbase = QKP + (w & 7) * 4096 + ((w >= 8) ? 2048 : 0);
    #pragma unroll
    for (int ct = 0; ct < 2; ++ct) {
      const int ctg = 2 * w + ct;
      f32x4 bias = *(const f32x4*)(b_qkv + ctg * 16 + hi * 4);
      #pragma unroll
      for (int rt = 0; rt < 4; ++rt) {
        f32x4 v = acc[ct][rt] + bias;
        int hi2 = ct * 2 + (hi >> 1);
        int eb = (hi & 1) * 4;
        *(uint2*)&pool[qkbase + (rt * 64 + hi2 * 16 + lo) * 8 + eb] =
            make_uint2(packbf(v[0], v[1]), packbf(v[2], v[3]));
      }
    }
    // epilogue v (swapped D: lane lo = channel, regs = tokens) -> packed b64 (R10-verified)
    {
      const int vhead = w >> 1, dblk = w & 1;
      const float bv = b_qkv[ctv * 16 + lo];
      #pragma unroll
      for (int rt = 0; rt < 4; ++rt) {
        f32x4 v = acc[2][rt];
        float v0 = v[0] + bv, v1 = v[1] + bv, v2 = v[2] + bv, v3 = v[3] + bv;
        int f = dblk * 2 + (rt >> 1);
        int hiR = (rt & 1) * 2 + (hi >> 1);
        int eb = (hi & 1) * 4;
        *(uint2*)&pool[VTF + (f * 8 + vhead) * 512 + (hiR * 16 + lo) * 8 + eb] =
            make_uint2(packbf(v0, v1), packbf(v2, v3));
      }
    }
  }
  __syncthreads();   // (b) q/k/v visible; XF dead (y may overwrite)

  // ---- phase 2+3: S^T tiles (it0..it0+1) + softmax; p in registers ----
  float rs0 = 0.f, rs1 = 0.f;
  unsigned pkp[4][2][2];
  {
    const float SC = 0.17677669529663687f * LOG2E;
    short8 ka0 = *(const short8*)&pool[QKP + h * 4096 + 2048 + ((it0 + 0) * 64 + lane) * 8];
    short8 ka1 = *(const short8*)&pool[QKP + h * 4096 + 2048 + ((it0 + 1) * 64 + lane) * 8];
    const float* bh = biasf + h * 4096;
    #pragma unroll
    for (int jt = 0; jt < 4; ++jt) {
      short8 qa = *(const short8*)&pool[QKP + h * 4096 + (jt * 64 + lane) * 8];
      f32x4 s0 = __builtin_amdgcn_mfma_f32_16x16x32_bf16(qa, ka0, zf, 0, 0, 0);
      f32x4 s1 = __builtin_amdgcn_mfma_f32_16x16x32_bf16(qa, ka1, zf, 0, 0, 0);
      {
        const int t = (it0 + 0) * 4 + jt;
        f32x4 bm = *(const f32x4*)&bh[(t * 64 + lane) * 4];
        f32x4 mm = *(const f32x4*)&mkf[(t * 64 + lane) * 4];
        float p0 = exp2f(fmaf(s0[0], SC, bm[0] + mm[0]));
        float p1 = exp2f(fmaf(s0[1], SC, bm[1] + mm[1]));
        float p2 = exp2f(fmaf(s0[2], SC, bm[2] + mm[2]));
        float p3 = exp2f(fmaf(s0[3], SC, bm[3] + mm[3]));
        rs0 += (p0 + p1) + (p2 + p3);
        pkp[jt][0][0] = packbf(p0, p1);
        pkp[jt][0][1] = packbf(p2, p3);
      }
      {
        const int t = (it0 + 1) * 4 + jt;
        f32x4 bm = *(const f32x4*)&bh[(t * 64 + lane) * 4];
        f32x4 mm = *(const f32x4*)&mkf[(t * 64 + lane) * 4];
        float p0 = exp2f(fmaf(s1[0], SC, bm[0] + mm[0]));
        float p1 = exp2f(fmaf(s1[1], SC, bm[1] + mm[1]));
        float p2 = exp2f(fmaf(s1[2], SC, bm[2] + mm[2]));
        float p3 = exp2f(fmaf(s1[3], SC, bm[3] + mm[3]));
        rs1 += (p0 + p1) + (p2 + p3);
        pkp[jt][1][0] = packbf(p0, p1);
        pkp[jt][1][1] = packbf(p2, p3);
      }
    }
  }
  float inv0, inv1;
  {
    float r2 = rs0 + __shfl_xor(rs0, 16);
    inv0 = 1.f / (r2 + __shfl_xor(r2, 32));
    float r3 = rs1 + __shfl_xor(rs1, 16);
    inv1 = 1.f / (r3 + __shfl_xor(r3, 32));
  }

  // ---- phase 4: PV; pb via shfl; y frags -> XF ----
  {
    const int srcA = lo + 32 * (hi & 1);
    const int srcB = srcA + 16;
    const bool cSel = (hi & 2) != 0;
    short8 va[2][2];
    #pragma unroll
    for (int dblk = 0; dblk < 2; ++dblk)
      #pragma unroll
      for (int k2 = 0; k2 < 2; ++k2)
        va[dblk][k2] = *(const short8*)&pool[VTF + ((dblk * 2 + k2) * 8 + h) * 512 + lane * 8];
    f32x4 ya[2][2];
    ya[0][0] = zf; ya[0][1] = zf; ya[1][0] = zf; ya[1][1] = zf;
    #pragma unroll
    for (int itL = 0; itL < 2; ++itL)
      #pragma unroll
      for (int k2 = 0; k2 < 2; ++k2) {
        short8 pb = asm_frag(pkp[2 * k2][itL][0], pkp[2 * k2][itL][1],
                             pkp[2 * k2 + 1][itL][0], pkp[2 * k2 + 1][itL][1], srcA, srcB, cSel);
        ya[0][itL] = __builtin_amdgcn_mfma_f32_16x16x32_bf16(va[0][k2], pb, ya[0][itL], 0, 0, 0);
        ya[1][itL] = __builtin_amdgcn_mfma_f32_16x16x32_bf16(va[1][k2], pb, ya[1][itL], 0, 0, 0);
      }
    #pragma unroll
    for (int itL = 0; itL < 2; ++itL) {
      const float iv = itL ? inv1 : inv0;
      #pragma unroll
      for (int dblk = 0; dblk < 2; ++dblk) {
        f32x4 yy = ya[dblk][itL];
        int hi2 = dblk * 2 + (hi >> 1);
        int eb = (hi & 1) * 4;
        *(uint2*)&pool[XF + (((it0 + itL) * 8 + h) * 64 + hi2 * 16 + lo) * 8 + eb] =
            make_uint2(packbf(yy[0] * iv, yy[1] * iv), packbf(yy[2] * iv, yy[3] * iv));
      }
    }
  }
  __syncthreads();   // (c) y frags ready

  // ---- phase 5: output projection, 1 ctg per wave ----
  {
    f32x4 pacc[4];
    pacc[0] = zf; pacc[1] = zf; pacc[2] = zf; pacc[3] = zf;
    #pragma unroll
    for (int ks = 0; ks < 8; ++ks) {
      short8 wf = *(const short8*)&woTf[((size_t)(w * 8 + ks) * 64 + lane) * 8];
      #pragma unroll
      for (int rt = 0; rt < 4; ++rt) {
        short8 yb = *(const short8*)&pool[XF + ((rt * 8 + ks) * 64 + lane) * 8];
        pacc[rt] = __builtin_amdgcn_mfma_f32_16x16x32_bf16(wf, yb, pacc[rt], 0, 0, 0);
      }
    }
    float* og = out + (size_t)b * (NTOK * 256);
    const int cb = w * 16 + hi * 4;
    f32x4 bb = *(const f32x4*)(b_out + cb);
    #pragma unroll
    for (int rt = 0; rt < 4; ++rt) {
      const int r = rt * 16 + lo;
      if (r < NTOK) {
        f32x4 vv = pacc[rt] + bb;
        *(f32x4*)(og + (size_t)r * 256 + cb) = vv;
      }
    }
  }
}

extern "C" void kernel_launch(void* const* d_in, const int* in_sizes, int n_in,
                              void* d_out, int out_size, void* d_ws, size_t ws_size,
                              hipStream_t stream) {
  const float *x = nullptr, *mask = nullptr, *w_qkv = nullptr, *b_qkv = nullptr,
              *rel_t = nullptr, *w_out = nullptr, *b_out = nullptr;
  for (int i = 0; i < n_in; ++i) {
    const float* p = (const float*)d_in[i];
    switch (in_sizes[i]) {
      case 4096 * 49 * 256: x = p; break;
      case 64 * 49 * 49:    mask = p; break;
      case 256 * 768:       w_qkv = p; break;
      case 768:             b_qkv = p; break;
      case 169 * 8:         rel_t = p; break;
      case 256 * 256:       w_out = p; break;
      case 256:             b_out = p; break;
    }
  }
  char* wsb = (char*)d_ws;
  u16* wqTf    = (u16*)(wsb + WS_WQT);
  u16* woTf    = (u16*)(wsb + WS_WOT);
  float* biasf = (float*)(wsb + WS_BIAS);
  float* mkg   = (float*)(wsb + WS_MKG);

  hipLaunchKernelGGL(prep_kernel, dim3(1024), dim3(256), 0, stream,
                     w_qkv, w_out, rel_t, mask, wqTf, woTf, biasf, mkg);
  hipLaunchKernelGGL(winattn_mfma, dim3(NBLK), dim3(1024), 0, stream,
                     x, b_qkv, b_out, wqTf, woTf, biasf, mkg, (float*)d_out);
}